// Round 3
// baseline (2053.335 us; speedup 1.0000x reference)
//
#include <hip/hip_runtime.h>
#include <hip/hip_cooperative_groups.h>
#include <math.h>

namespace cg = cooperative_groups;

#define BB 256
#define DD 256
#define VV 2000
#define VT 10000
#define OPTN 16
#define SEQN 10
#define SRCN 40
#define D3 768
#define D2 512
#define WPR 320   // mask words per row (10000 bits padded)

#define LOG_TINY (-29.9336062f)

// output offsets (floats)
#define OFF_OPTS  (2*BB + BB*OPTN*4*SEQN)          // 164352
#define OFF_TOPO  (OFF_OPTS + BB*OPTN)             // 168448
#define OFF_EXACT (OFF_TOPO + 4*BB*SEQN)           // 178688

typedef __bf16 bf16x8 __attribute__((ext_vector_type(8)));
typedef float  f32x4  __attribute__((ext_vector_type(4)));

__device__ __forceinline__ float sigm(float x){ return 1.0f/(1.0f+expf(-x)); }
__device__ __forceinline__ unsigned short f2bf(float x){
  union { float f; unsigned int u; } v; v.f = x;
  unsigned int r = (v.u + 0x7FFF + ((v.u >> 16) & 1)) >> 16;
  return (unsigned short)r;
}

struct CoopArgs {
  const int* lhs; const int* gg;
  const float* tree_state; const float* emb; const float* mem;
  const float* Wx; const float* Wh; const float* bx; const float* bh;
  const float* Wc; const float* bc; const float* Wsym; const float* bsym;
  float* EW; float* gh; float* X; float* soa; float* ts; float* cl;
  float* out; int* sym_i; unsigned short* Abf;
};

// ---- phase 0: EW = emb@Wx (rows 0..1999) and gh = ts0@Wh + bh, unified 64x64 fp32 tiles
__device__ void phase0(const CoopArgs& a){
  __shared__ float As[16][64];
  __shared__ float Bs[16][64];
  int tid = threadIdx.x;
  int tx = tid & 15, ty = tid >> 4;
  for(int tile = blockIdx.x; tile < 36*12; tile += 256){
    int mt = tile/12, nt = tile%12;
    int m0 = mt*64, n0 = nt*64;
    bool isGH = (mt >= 32);
    const float* Bmat = isGH ? a.Wh : a.Wx;
    float acc[4][4];
    #pragma unroll
    for(int i=0;i<4;i++){ acc[i][0]=0.f; acc[i][1]=0.f; acc[i][2]=0.f; acc[i][3]=0.f; }
    for(int k0=0;k0<DD;k0+=16){
      {
        int row = tid >> 2, kk = (tid & 3)*4;
        float4 av = {0,0,0,0};
        if(isGH){
          int m2 = m0 - 2048 + row;
          av = *(const float4*)&a.tree_state[m2*DD + k0 + kk];
        } else {
          int m = m0 + row;
          if(m < VV) av = *(const float4*)&a.emb[m*DD + k0 + kk];
        }
        As[kk+0][row]=av.x; As[kk+1][row]=av.y; As[kk+2][row]=av.z; As[kk+3][row]=av.w;
      }
      {
        int r = tid >> 4, c2 = (tid & 15)*4;
        float4 bv = *(const float4*)&Bmat[(k0+r)*D3 + n0 + c2];
        *(float4*)&Bs[r][c2] = bv;
      }
      __syncthreads();
      #pragma unroll
      for(int k=0;k<16;k++){
        float4 a4 = *(const float4*)&As[k][ty*4];
        float4 b4 = *(const float4*)&Bs[k][tx*4];
        float av[4] = {a4.x,a4.y,a4.z,a4.w};
        float bw[4] = {b4.x,b4.y,b4.z,b4.w};
        #pragma unroll
        for(int i=0;i<4;i++)
          #pragma unroll
          for(int j=0;j<4;j++) acc[i][j] = fmaf(av[i], bw[j], acc[i][j]);
      }
      __syncthreads();
    }
    #pragma unroll
    for(int i=0;i<4;i++){
      int m = m0 + ty*4 + i;
      if(isGH){
        int m2 = m - 2048;
        #pragma unroll
        for(int j=0;j<4;j++) a.gh[m2*D3 + n0 + tx*4 + j] = acc[i][j] + a.bh[n0 + tx*4 + j];
      } else if(m < VV){
        #pragma unroll
        for(int j=0;j<4;j++) a.EW[m*D3 + n0 + tx*4 + j] = acc[i][j];
      }
    }
  }
}

// ---- phase A: per-b argmax(cl[t-1]) -> sym; GRU; attention; write X=[ctx|h]
__device__ void phaseA(int t, const CoopArgs& a){
  int b = blockIdx.x, tid = threadIdx.x;
  __shared__ float hs[DD], sc[SRCN];
  __shared__ float wmx[4]; __shared__ int wmi[4];
  __shared__ int sym_sh;
  int lane = tid & 63, wv = tid >> 6;
  int sym;
  if(t == 0){
    sym = a.lhs[b];
  } else {
    const float* row = a.cl + ((size_t)(t-1)*BB + b)*VV;
    float mx = -1e30f; int mi = 0;
    for(int v=tid; v<VV; v+=256){
      float val = row[v];
      if(val > mx){ mx = val; mi = v; }
    }
    for(int off=32; off; off>>=1){
      float ox = __shfl_down(mx, off, 64);
      int   oi = __shfl_down(mi, off, 64);
      if(ox > mx || (ox == mx && oi < mi)){ mx = ox; mi = oi; }
    }
    if(lane==0){ wmx[wv]=mx; wmi[wv]=mi; }
    __syncthreads();
    if(tid==0){
      float bmx = wmx[0]; int bmi = wmi[0];
      for(int w=1;w<4;w++){
        if(wmx[w] > bmx || (wmx[w]==bmx && wmi[w] < bmi)){ bmx=wmx[w]; bmi=wmi[w]; }
      }
      sym_sh = bmi;
    }
    __syncthreads();
    sym = sym_sh;
  }
  const float* ew  = a.EW + sym*D3;
  const float* ghb = a.gh + b*D3;
  float r = sigm(ew[tid]      + a.bx[tid]      + ghb[tid]);
  float z = sigm(ew[256+tid]  + a.bx[256+tid]  + ghb[256+tid]);
  float n = tanhf(ew[512+tid] + a.bx[512+tid]  + r*ghb[512+tid]);
  float h = (1.0f - z)*n + z*a.tree_state[b*DD + tid];
  hs[tid] = h;
  __syncthreads();
  for(int s = wv; s < SRCN; s += 4){
    float p = 0.f;
    const float* mrow = a.mem + (size_t)(b*SRCN + s)*DD;
    #pragma unroll 4
    for(int d = lane; d < DD; d += 64) p = fmaf(hs[d], mrow[d], p);
    for(int off=32; off; off>>=1) p += __shfl_down(p, off, 64);
    if(lane==0) sc[s] = p;
  }
  __syncthreads();
  if(tid==0){
    float mx = sc[0];
    for(int s=1;s<SRCN;s++) mx = fmaxf(mx, sc[s]);
    float sum = 0.f;
    for(int s=0;s<SRCN;s++){ float e = expf(sc[s]-mx); sc[s]=e; sum+=e; }
    float inv = 1.0f/sum;
    for(int s=0;s<SRCN;s++) sc[s]*=inv;
  }
  __syncthreads();
  float c = 0.f;
  #pragma unroll 8
  for(int s=0;s<SRCN;s++) c = fmaf(sc[s], a.mem[(size_t)(b*SRCN+s)*DD + tid], c);
  a.X[b*D2 + tid]      = c;
  a.X[b*D2 + DD + tid] = h;
}

// ---- phase B: soa = tanh(X@Wc + bc); ts = tanh(ts + soa). 64 blocks, 32x32 tiles, K=512
__device__ void phaseB(const CoopArgs& a){
  int blk = blockIdx.x, tid = threadIdx.x;
  if(blk < 64){
    __shared__ float As[16][33];
    __shared__ float Bs[16][32];
    int m0 = (blk>>3)*32, n0 = (blk&7)*32;
    int tx = tid & 15, ty = tid >> 4;
    float a00=0.f,a01=0.f,a10=0.f,a11=0.f;
    for(int k0=0;k0<D2;k0+=16){
      for(int i2 = tid; i2 < 512; i2 += 256){
        int mm = i2>>4, kk = i2&15;
        As[kk][mm] = a.X[(m0+mm)*D2 + k0 + kk];
      }
      for(int i2 = tid; i2 < 512; i2 += 256){
        int kk = i2>>5, nn = i2&31;
        Bs[kk][nn] = a.Wc[(k0+kk)*DD + n0 + nn];
      }
      __syncthreads();
      #pragma unroll
      for(int k=0;k<16;k++){
        float x0 = As[k][ty*2], x1 = As[k][ty*2+1];
        float w0 = Bs[k][tx*2], w1 = Bs[k][tx*2+1];
        a00 = fmaf(x0,w0,a00); a01 = fmaf(x0,w1,a01);
        a10 = fmaf(x1,w0,a10); a11 = fmaf(x1,w1,a11);
      }
      __syncthreads();
    }
    int m = m0 + ty*2, nn = n0 + tx*2;
    float accs[2][2] = {{a00,a01},{a10,a11}};
    #pragma unroll
    for(int i=0;i<2;i++)
      #pragma unroll
      for(int j=0;j<2;j++){
        float s = tanhf(accs[i][j] + a.bc[nn+j]);
        a.soa[(m+i)*DD + nn+j] = s;
        a.ts[(m+i)*DD + nn+j]  = tanhf(a.ts[(m+i)*DD + nn+j] + s);
      }
  }
}

// ---- phase C: cl[t] = soa@Wsym + bsym + mask. 128 blocks, 64x64 tiles
__device__ void phaseC(int t, const CoopArgs& a){
  int blk = blockIdx.x, tid = threadIdx.x;
  if(blk < 128){
    __shared__ float As[16][64];
    __shared__ float Bs[16][64];
    __shared__ int sel[64][OPTN];
    int tx = tid & 15, ty = tid >> 4;
    int m0 = (blk>>5)*64, n0 = (blk&31)*64;
    for(int idx = tid; idx < 64*OPTN; idx += 256){
      int i = idx >> 4, o = idx & 15;
      int bb = m0 + i;
      int base = ((bb*OPTN + o)*4)*SEQN + t;
      int mk = a.gg[base + 3*SEQN];
      sel[i][o] = mk ? a.gg[base] : -1;
    }
    float acc[4][4];
    #pragma unroll
    for(int i=0;i<4;i++){ acc[i][0]=0.f; acc[i][1]=0.f; acc[i][2]=0.f; acc[i][3]=0.f; }
    for(int k0=0;k0<DD;k0+=16){
      {
        int row = tid >> 2, kk = (tid & 3)*4;
        float4 av = *(const float4*)&a.soa[(m0+row)*DD + k0 + kk];
        As[kk+0][row]=av.x; As[kk+1][row]=av.y; As[kk+2][row]=av.z; As[kk+3][row]=av.w;
      }
      {
        int r = tid >> 4, c2 = (tid & 15)*4;
        int n = n0 + c2;
        float4 bv;
        if(n + 3 < VV){ bv = *(const float4*)&a.Wsym[(k0+r)*VV + n]; }
        else {
          bv.x = (n+0<VV)? a.Wsym[(k0+r)*VV + n+0] : 0.f;
          bv.y = (n+1<VV)? a.Wsym[(k0+r)*VV + n+1] : 0.f;
          bv.z = (n+2<VV)? a.Wsym[(k0+r)*VV + n+2] : 0.f;
          bv.w = (n+3<VV)? a.Wsym[(k0+r)*VV + n+3] : 0.f;
        }
        *(float4*)&Bs[r][c2] = bv;
      }
      __syncthreads();
      #pragma unroll
      for(int k=0;k<16;k++){
        float4 a4 = *(const float4*)&As[k][ty*4];
        float4 b4 = *(const float4*)&Bs[k][tx*4];
        float av[4] = {a4.x,a4.y,a4.z,a4.w};
        float bw[4] = {b4.x,b4.y,b4.z,b4.w};
        #pragma unroll
        for(int i=0;i<4;i++)
          #pragma unroll
          for(int j=0;j<4;j++) acc[i][j] = fmaf(av[i], bw[j], acc[i][j]);
      }
      __syncthreads();
    }
    #pragma unroll
    for(int i=0;i<4;i++){
      int m = m0 + ty*4 + i;
      #pragma unroll
      for(int j=0;j<4;j++){
        int n = n0 + tx*4 + j;
        if(n < VV){
          bool allowed = false;
          #pragma unroll
          for(int o=0;o<OPTN;o++) allowed |= (sel[ty*4+i][o] == n);
          a.cl[((size_t)t*BB + m)*VV + n] = acc[i][j] + a.bsym[n] + (allowed? 0.f : LOG_TINY);
        }
      }
    }
  }
}

// ---- phase D: lse over t; opts_logp; best; topo; sym_i; Abf build
__device__ void phaseD(const CoopArgs& a){
  int b = blockIdx.x, tid = threadIdx.x;
  __shared__ float red[256];
  __shared__ float lse_sh[SEQN];
  __shared__ float sacc[OPTN];
  __shared__ int ssym[SEQN];
  __shared__ int sbest;
  for(int t=0;t<SEQN;t++){
    const float* row = a.cl + ((size_t)t*BB + b)*VV;
    float mx = -1e30f;
    for(int v=tid; v<VV; v+=256) mx = fmaxf(mx, row[v]);
    red[tid]=mx; __syncthreads();
    for(int s=128;s;s>>=1){ if(tid<s) red[tid]=fmaxf(red[tid],red[tid+s]); __syncthreads(); }
    float gmx = red[0]; __syncthreads();
    float sum = 0.f;
    for(int v=tid; v<VV; v+=256) sum += expf(row[v]-gmx);
    red[tid]=sum; __syncthreads();
    for(int s=128;s;s>>=1){ if(tid<s) red[tid]+=red[tid+s]; __syncthreads(); }
    if(tid==0) lse_sh[t] = gmx + logf(red[0]);
    __syncthreads();
  }
  if(tid < OPTN){
    int o = tid;
    float acc = 0.f;
    for(int t=0;t<SEQN;t++){
      int base = ((b*OPTN + o)*4)*SEQN + t;
      int mk = a.gg[base + 3*SEQN];
      if(mk){
        int v = a.gg[base];
        float p = expf(a.cl[((size_t)t*BB + b)*VV + v] - lse_sh[t]);
        acc += logf(p + 1e-13f);
      }
    }
    sacc[o] = acc;
    a.out[OFF_OPTS + b*OPTN + o] = acc;
  }
  __syncthreads();
  if(tid==0){
    float mx = sacc[0]; int mi = 0;
    for(int o=1;o<OPTN;o++) if(sacc[o] > mx){ mx = sacc[o]; mi = o; }
    sbest = mi;
  }
  __syncthreads();
  if(tid < 4*SEQN){
    int c = tid/SEQN, t = tid%SEQN;
    int val = a.gg[((b*OPTN + sbest)*4 + c)*SEQN + t];
    a.out[OFF_TOPO + c*(BB*SEQN) + b*SEQN + t] = (float)val;
    if(c==0){ a.sym_i[b*SEQN + t] = val; ssym[t] = val; }
  }
  __syncthreads();
  for(int idx = tid; idx < SEQN*D2; idx += 256){
    int t = idx >> 9, k = idx & 511;
    float val = (k < DD) ? a.emb[ssym[t]*DD + k] : a.ts[b*DD + (k-DD)];
    a.Abf[(size_t)(b*SEQN + t)*D2 + k] = f2bf(val);
  }
}

__global__ __launch_bounds__(256) void k_coop(CoopArgs a){
  cg::grid_group grid = cg::this_grid();
  phase0(a);
  grid.sync();
  for(int t=0; t<SEQN; t++){
    phaseA(t, a);
    grid.sync();
    phaseB(a);
    grid.sync();
    phaseC(t, a);
    grid.sync();
  }
  phaseD(a);
}

// ---- passthrough outputs 0..2 as float
__global__ void k_pass(const int* __restrict__ lhs, const int* __restrict__ lhs_mask,
                       const int* __restrict__ gg, float* __restrict__ out){
  int i = blockIdx.x*256 + threadIdx.x;
  if(i < BB) out[i] = (float)lhs[i];
  else if(i < 2*BB) out[i] = (float)lhs_mask[i - BB];
  else if(i < 2*BB + BB*OPTN*4*SEQN) out[i] = (float)gg[i - 2*BB];
}

// ---- Wtok [512][10000] fp32 -> WtokB [10000][512] bf16
__global__ void k_wtokT(const float* __restrict__ Wtok, unsigned short* __restrict__ WtokB){
  __shared__ float tile[32][65];
  int tid = threadIdx.x;
  int n0 = blockIdx.x*64, k0 = blockIdx.y*32;
  #pragma unroll
  for(int p=0;p<8;p++){
    int idx = tid + p*256;
    int kk = idx >> 6, nn = idx & 63;
    int n = n0 + nn;
    tile[kk][nn] = (n < VT) ? Wtok[(size_t)(k0+kk)*VT + n] : 0.f;
  }
  __syncthreads();
  #pragma unroll
  for(int p=0;p<4;p++){
    int idx = tid + p*256;
    int nn = idx >> 4, kk = (idx & 15)*2;
    int n = n0 + nn;
    if(n < VT){
      ushort2 v;
      v.x = f2bf(tile[kk][nn]);
      v.y = f2bf(tile[kk+1][nn]);
      *(ushort2*)&WtokB[(size_t)n*D2 + k0 + kk] = v;
    }
  }
}

// ---- pack binary tok_table into bitmask (2000 x 320 words)
__global__ void k_tokpack(const float* __restrict__ tok_table, unsigned int* __restrict__ maskp){
  int v = blockIdx.x;
  int tid = threadIdx.x, lane = tid & 63, wv = tid >> 6;
  for(int n0 = wv*64; n0 < VT; n0 += 256){
    int n = n0 + lane;
    float val = (n < VT) ? tok_table[(size_t)v*VT + n] : 0.f;
    unsigned long long m = __ballot(val != 0.f);
    if(lane == 0)  maskp[v*WPR + (n0>>5)]     = (unsigned int)m;
    if(lane == 32) maskp[v*WPR + (n0>>5) + 1] = (unsigned int)(m >> 32);
  }
}

// ---- exact_logit: bf16 MFMA GEMM 2560x10000 K=512 + bitmask epilogue, LDS-coalesced stores
__global__ __launch_bounds__(256) void k_tok_mfma(
    const unsigned short* __restrict__ A, const unsigned short* __restrict__ Bw,
    const float* __restrict__ btok, const unsigned int* __restrict__ maskp,
    const int* __restrict__ sym_i, float* __restrict__ out){
  __shared__ unsigned short As[128*40];
  __shared__ unsigned short Bs[128*40];
  __shared__ float Cs[32][132];
  __shared__ float Bt[128];
  int tid = threadIdx.x;
  int lane = tid & 63, wave = tid >> 6;
  int c = lane & 15, q = lane >> 4;
  int wm = (wave >> 1)*64, wn = (wave & 1)*64;
  int m0 = blockIdx.y*128, n0 = blockIdx.x*128;
  if(tid < 128) Bt[tid] = (n0+tid < VT) ? btok[n0+tid] : 0.f;
  f32x4 acc[4][4];
  #pragma unroll
  for(int i=0;i<4;i++)
    #pragma unroll
    for(int j=0;j<4;j++) acc[i][j] = (f32x4){0.f,0.f,0.f,0.f};

  for(int k0=0;k0<D2;k0+=32){
    #pragma unroll
    for(int ci = tid; ci < 512; ci += 256){
      int row = ci >> 2, ko = (ci & 3)*8;
      float4 av = *(const float4*)(A + (size_t)(m0+row)*D2 + k0 + ko);
      *(float4*)(As + row*40 + ko) = av;
      int n = n0 + row;
      float4 bv = {0,0,0,0};
      if(n < VT) bv = *(const float4*)(Bw + (size_t)n*D2 + k0 + ko);
      *(float4*)(Bs + row*40 + ko) = bv;
    }
    __syncthreads();
    bf16x8 af[4], bf[4];
    #pragma unroll
    for(int i=0;i<4;i++) af[i] = *(const bf16x8*)(As + (wm + i*16 + c)*40 + q*8);
    #pragma unroll
    for(int j=0;j<4;j++) bf[j] = *(const bf16x8*)(Bs + (wn + j*16 + c)*40 + q*8);
    #pragma unroll
    for(int i=0;i<4;i++)
      #pragma unroll
      for(int j=0;j<4;j++)
        acc[i][j] = __builtin_amdgcn_mfma_f32_16x16x32_bf16(af[i], bf[j], acc[i][j], 0, 0, 0);
    __syncthreads();
  }
  // epilogue: 4 chunks of 32 rows (16 from each m-half), LDS bounce + coalesced stores
  for(int ch=0; ch<4; ch++){
    int rbase = (wm ? 16 : 0);
    #pragma unroll
    for(int j=0;j<4;j++)
      #pragma unroll
      for(int r=0;r<4;r++)
        Cs[rbase + q*4 + r][wn + j*16 + c] = acc[ch][j][r];
    __syncthreads();
    int col4 = (tid & 31)*4;
    int rowbase = (tid >> 5)*4;
    int n = n0 + col4;
    if(n < VT){
      #pragma unroll
      for(int g=0; g<4; g++){
        int rr = rowbase + g;
        int tr = (rr < 16) ? ch*16 + rr : 64 + ch*16 + (rr - 16);
        int m = m0 + tr;
        int s = sym_i[m];
        unsigned int w = maskp[s*WPR + (n0>>5) + (col4>>5)];
        float4 vv;
        vv.x = Cs[rr][col4+0] + Bt[col4+0] + (((w>>((col4+0)&31))&1) ? 0.f : LOG_TINY);
        vv.y = Cs[rr][col4+1] + Bt[col4+1] + (((w>>((col4+1)&31))&1) ? 0.f : LOG_TINY);
        vv.z = Cs[rr][col4+2] + Bt[col4+2] + (((w>>((col4+2)&31))&1) ? 0.f : LOG_TINY);
        vv.w = Cs[rr][col4+3] + Bt[col4+3] + (((w>>((col4+3)&31))&1) ? 0.f : LOG_TINY);
        *(float4*)&out[OFF_EXACT + (size_t)m*VT + n] = vv;
      }
    }
    __syncthreads();
  }
}

extern "C" void kernel_launch(void* const* d_in, const int* in_sizes, int n_in,
                              void* d_out, int out_size, void* d_ws, size_t ws_size,
                              hipStream_t stream) {
  const int*   lhs       = (const int*)  d_in[0];
  const int*   lhs_mask  = (const int*)  d_in[1];
  const float* tree_state= (const float*)d_in[2];
  const int*   gg        = (const int*)  d_in[3];
  const float* emb       = (const float*)d_in[4];
  const float* mem       = (const float*)d_in[5];
  const float* Wx        = (const float*)d_in[6];
  const float* Wh        = (const float*)d_in[7];
  const float* bx        = (const float*)d_in[8];
  const float* bh        = (const float*)d_in[9];
  const float* Wc        = (const float*)d_in[10];
  const float* bc        = (const float*)d_in[11];
  const float* Wsym      = (const float*)d_in[12];
  const float* bsym      = (const float*)d_in[13];
  const float* Wtok      = (const float*)d_in[14];
  const float* btok      = (const float*)d_in[15];
  const float* tok_table = (const float*)d_in[16];
  float* out = (float*)d_out;

  float* W    = (float*)d_ws;
  float* gh   = W;                         // 196608
  float* ts   = gh  + BB*D3;               // 65536
  float* soa  = ts  + BB*DD;               // 65536
  float* Xb   = soa + BB*DD;               // 131072
  float* cl   = Xb  + BB*D2;               // 5,120,000
  float* EW   = cl  + (size_t)SEQN*BB*VV;  // 1,536,000
  int*   sym_i= (int*)(EW + VV*D3);        // 2560
  unsigned short* Abf  = (unsigned short*)(sym_i + BB*SEQN);   // 2560*512 u16
  unsigned short* WtokB= Abf + (size_t)BB*SEQN*D2;             // 10000*512 u16
  unsigned int* maskp  = (unsigned int*)(WtokB + (size_t)VT*D2); // 2000*320 u32

  hipMemcpyAsync(ts, tree_state, BB*DD*sizeof(float), hipMemcpyDeviceToDevice, stream);

  k_pass<<<(2*BB + BB*OPTN*4*SEQN + 255)/256, 256, 0, stream>>>(lhs, lhs_mask, gg, out);
  k_wtokT<<<dim3((VT+63)/64, D2/32), 256, 0, stream>>>(Wtok, WtokB);
  k_tokpack<<<VV, 256, 0, stream>>>(tok_table, maskp);

  CoopArgs ca;
  ca.lhs = lhs; ca.gg = gg; ca.tree_state = tree_state; ca.emb = emb; ca.mem = mem;
  ca.Wx = Wx; ca.Wh = Wh; ca.bx = bx; ca.bh = bh; ca.Wc = Wc; ca.bc = bc;
  ca.Wsym = Wsym; ca.bsym = bsym;
  ca.EW = EW; ca.gh = gh; ca.X = Xb; ca.soa = soa; ca.ts = ts; ca.cl = cl;
  ca.out = out; ca.sym_i = sym_i; ca.Abf = Abf;
  void* kargs[] = { &ca };
  hipLaunchCooperativeKernel((void*)k_coop, dim3(256), dim3(256), kargs, 0, stream);

  k_tok_mfma<<<dim3((VT+127)/128, (BB*SEQN)/128), 256, 0, stream>>>(Abf, WtokB, btok, maskp, sym_i, out);
}

// Round 4
// 1115.450 us; speedup vs baseline: 1.8408x; 1.8408x over previous
//
#include <hip/hip_runtime.h>
#include <math.h>

#define BB 256
#define DD 256
#define VV 2000
#define VT 10000
#define OPTN 16
#define SEQN 10
#define SRCN 40
#define D3 768
#define D2 512
#define WPR 320
#define NBLK 256

#define LOG_TINY (-29.9336062f)

// output offsets (floats)
#define OFF_OPTS  (2*BB + BB*OPTN*4*SEQN)          // 164352
#define OFF_TOPO  (OFF_OPTS + BB*OPTN)             // 168448
#define OFF_EXACT (OFF_TOPO + 4*BB*SEQN)           // 178688

typedef __bf16 bf16x8 __attribute__((ext_vector_type(8)));
typedef float  f32x4  __attribute__((ext_vector_type(4)));

__device__ __forceinline__ float sigm(float x){ return 1.0f/(1.0f+expf(-x)); }
__device__ __forceinline__ unsigned short f2bf(float x){
  union { float f; unsigned int u; } v; v.f = x;
  unsigned int r = (v.u + 0x7FFF + ((v.u >> 16) & 1)) >> 16;
  return (unsigned short)r;
}

// ---- fast grid barrier: count + generation, agent-scope atomics ----
__device__ __forceinline__ void gbar(int* cnt, int* gen){
  __syncthreads();
  if(threadIdx.x == 0){
    __threadfence();  // flush prior stores toward device scope
    int g = __hip_atomic_load(gen, __ATOMIC_RELAXED, __HIP_MEMORY_SCOPE_AGENT);
    int a = __hip_atomic_fetch_add(cnt, 1, __ATOMIC_ACQ_REL, __HIP_MEMORY_SCOPE_AGENT);
    if(a == NBLK-1){
      __hip_atomic_store(cnt, 0, __ATOMIC_RELAXED, __HIP_MEMORY_SCOPE_AGENT);
      __hip_atomic_fetch_add(gen, 1, __ATOMIC_RELEASE, __HIP_MEMORY_SCOPE_AGENT);
    } else {
      while(__hip_atomic_load(gen, __ATOMIC_RELAXED, __HIP_MEMORY_SCOPE_AGENT) == g)
        __builtin_amdgcn_s_sleep(2);
      (void)__hip_atomic_load(gen, __ATOMIC_ACQUIRE, __HIP_MEMORY_SCOPE_AGENT);
    }
  }
  __syncthreads();
}

struct CoopArgs {
  const int* lhs; const int* gg;
  const float* tree_state; const float* emb; const float* mem;
  const float* Wx; const float* Wh; const float* bx; const float* bh;
  const float* bc; const float* Wsym; const float* bsym;
  float* EW; float* gh; float* soa; float* ts; float* cl; float* lse; float* WcT;
  float* out; int* sym_i; unsigned short* Abf;
  int* bcnt; int* bgen;
};

// ---- phase 0: EW = emb@Wx (2000x768) and gh = ts0@Wh + bh (256x768), 64x64 tiles
__device__ void phase0(const CoopArgs& a, float* sm){
  float* As = sm;          // [16][64]
  float* Bs = sm + 1024;   // [16][64]
  int tid = threadIdx.x;
  int tx = tid & 15, ty = tid >> 4;
  for(int tile = blockIdx.x; tile < 36*12; tile += NBLK){
    int mt = tile/12, nt = tile%12;
    int m0 = mt*64, n0 = nt*64;
    bool isGH = (mt >= 32);
    const float* Bmat = isGH ? a.Wh : a.Wx;
    float acc[4][4];
    #pragma unroll
    for(int i=0;i<4;i++){ acc[i][0]=0.f; acc[i][1]=0.f; acc[i][2]=0.f; acc[i][3]=0.f; }
    for(int k0=0;k0<DD;k0+=16){
      {
        int row = tid >> 2, kk = (tid & 3)*4;
        float4 av = {0,0,0,0};
        if(isGH){
          int m2 = m0 - 2048 + row;
          av = *(const float4*)&a.tree_state[m2*DD + k0 + kk];
        } else {
          int m = m0 + row;
          if(m < VV) av = *(const float4*)&a.emb[m*DD + k0 + kk];
        }
        As[(kk+0)*64+row]=av.x; As[(kk+1)*64+row]=av.y;
        As[(kk+2)*64+row]=av.z; As[(kk+3)*64+row]=av.w;
      }
      {
        int r = tid >> 4, c2 = (tid & 15)*4;
        float4 bv = *(const float4*)&Bmat[(k0+r)*D3 + n0 + c2];
        *(float4*)&Bs[r*64 + c2] = bv;
      }
      __syncthreads();
      #pragma unroll
      for(int k=0;k<16;k++){
        float4 a4 = *(const float4*)&As[k*64 + ty*4];
        float4 b4 = *(const float4*)&Bs[k*64 + tx*4];
        float av[4] = {a4.x,a4.y,a4.z,a4.w};
        float bw[4] = {b4.x,b4.y,b4.z,b4.w};
        #pragma unroll
        for(int i=0;i<4;i++)
          #pragma unroll
          for(int j=0;j<4;j++) acc[i][j] = fmaf(av[i], bw[j], acc[i][j]);
      }
      __syncthreads();
    }
    #pragma unroll
    for(int i=0;i<4;i++){
      int m = m0 + ty*4 + i;
      if(isGH){
        int m2 = m - 2048;
        #pragma unroll
        for(int j=0;j<4;j++) a.gh[m2*D3 + n0 + tx*4 + j] = acc[i][j] + a.bh[n0 + tx*4 + j];
      } else if(m < VV){
        #pragma unroll
        for(int j=0;j<4;j++) a.EW[m*D3 + n0 + tx*4 + j] = acc[i][j];
      }
    }
  }
}

// ---- phase A: per-batch. argmax+online-LSE over cl[t-1]; GRU; attention; proj GEMV; ts update
__device__ void phaseA(int t, const CoopArgs& a, float* sm){
  float* Xs   = sm;                 // [512]: [ctx | h]
  float* sc   = sm + 512;          // [40]
  float* rmx  = sm + 576;          // [256]
  float* rsum = sm + 832;          // [256]
  int*   ridx = (int*)(sm + 1088); // [256]
  int b = blockIdx.x, tid = threadIdx.x;
  int lane = tid & 63, wv = tid >> 6;
  int sym;
  if(t == 0){
    sym = a.lhs[b];
  } else {
    const float* row = a.cl + ((size_t)(t-1)*BB + b)*VV;
    float mx = -1e30f, sm_ = 0.f; int mi = 0;
    for(int v=tid; v<VV; v+=NBLK){
      float val = row[v];
      if(val > mx){ sm_ = sm_*expf(mx - val) + 1.0f; mx = val; mi = v; }
      else sm_ += expf(val - mx);
    }
    rmx[tid]=mx; rsum[tid]=sm_; ridx[tid]=mi;
    __syncthreads();
    for(int s=128; s; s>>=1){
      if(tid < s){
        float m1=rmx[tid], s1=rsum[tid]; int i1=ridx[tid];
        float m2=rmx[tid+s], s2=rsum[tid+s]; int i2=ridx[tid+s];
        float M = fmaxf(m1,m2);
        float S = s1*expf(m1-M) + s2*expf(m2-M);
        int I = (m2>m1) ? i2 : ((m2==m1 && i2<i1) ? i2 : i1);
        rmx[tid]=M; rsum[tid]=S; ridx[tid]=I;
      }
      __syncthreads();
    }
    sym = ridx[0];
    if(tid==0) a.lse[(t-1)*BB + b] = rmx[0] + logf(rsum[0]);
  }
  const float* ew  = a.EW + sym*D3;
  const float* ghb = a.gh + b*D3;
  float r = sigm(ew[tid]      + a.bx[tid]      + ghb[tid]);
  float z = sigm(ew[256+tid]  + a.bx[256+tid]  + ghb[256+tid]);
  float n = tanhf(ew[512+tid] + a.bx[512+tid]  + r*ghb[512+tid]);
  float h = (1.0f - z)*n + z*a.tree_state[b*DD + tid];
  Xs[256 + tid] = h;
  __syncthreads();
  for(int s = wv; s < SRCN; s += 4){
    float p = 0.f;
    const float* mrow = a.mem + (size_t)(b*SRCN + s)*DD;
    #pragma unroll 4
    for(int d = lane; d < DD; d += 64) p = fmaf(Xs[256+d], mrow[d], p);
    for(int off=32; off; off>>=1) p += __shfl_down(p, off, 64);
    if(lane==0) sc[s] = p;
  }
  __syncthreads();
  if(tid==0){
    float mx = sc[0];
    for(int s=1;s<SRCN;s++) mx = fmaxf(mx, sc[s]);
    float sum = 0.f;
    for(int s=0;s<SRCN;s++){ float e = expf(sc[s]-mx); sc[s]=e; sum+=e; }
    float inv = 1.0f/sum;
    for(int s=0;s<SRCN;s++) sc[s]*=inv;
  }
  __syncthreads();
  float c = 0.f;
  #pragma unroll 8
  for(int s=0;s<SRCN;s++) c = fmaf(sc[s], a.mem[(size_t)(b*SRCN+s)*DD + tid], c);
  Xs[tid] = c;
  __syncthreads();
  // proj: soa[b][tid] = tanh(X . WcT[tid] + bc[tid]);  WcT row = 512 contiguous floats
  float acc = a.bc[tid];
  const float* wr = a.WcT + (size_t)tid*D2;
  #pragma unroll 8
  for(int k=0;k<D2;k+=4){
    float4 w4 = *(const float4*)&wr[k];
    float4 x4 = *(const float4*)&Xs[k];
    acc = fmaf(w4.x,x4.x,acc); acc = fmaf(w4.y,x4.y,acc);
    acc = fmaf(w4.z,x4.z,acc); acc = fmaf(w4.w,x4.w,acc);
  }
  float s = tanhf(acc);
  a.soa[b*DD + tid] = s;
  a.ts[b*DD + tid]  = tanhf(a.ts[b*DD + tid] + s);
}

// ---- phase C: cl[t] = soa@Wsym + bsym + mask. 256 blocks, 32x64 tiles, K=256
__device__ void phaseC(int t, const CoopArgs& a, float* sm){
  float* As = sm;                   // [16][33] padded
  float* Bs = sm + 544;             // [16][64]
  int*  sel = (int*)(sm + 1568);    // [32][16]
  int blk = blockIdx.x, tid = threadIdx.x;
  int tx = tid & 15, ty = tid >> 4;   // ty in [0,16): rows ty*2, ty*2+1
  int m0 = (blk >> 5)*32, n0 = (blk & 31)*64;
  for(int idx = tid; idx < 32*OPTN; idx += NBLK){
    int i = idx >> 4, o = idx & 15;
    int bb = m0 + i;
    int base = ((bb*OPTN + o)*4)*SEQN + t;
    int mk = a.gg[base + 3*SEQN];
    sel[idx] = mk ? a.gg[base] : -1;
  }
  float a00=0.f,a01=0.f,a02=0.f,a03=0.f;
  float a10=0.f,a11=0.f,a12=0.f,a13=0.f;
  for(int k0=0;k0<DD;k0+=16){
    if(tid < 128){
      int row = tid >> 2, kk = (tid & 3)*4;
      float4 av = *(const float4*)&a.soa[(m0+row)*DD + k0 + kk];
      As[(kk+0)*33+row]=av.x; As[(kk+1)*33+row]=av.y;
      As[(kk+2)*33+row]=av.z; As[(kk+3)*33+row]=av.w;
    }
    {
      int r = tid >> 4, c4 = (tid & 15)*4;
      int n = n0 + c4;
      float4 bv;
      if(n + 3 < VV){ bv = *(const float4*)&a.Wsym[(k0+r)*VV + n]; }
      else {
        bv.x = (n+0<VV)? a.Wsym[(k0+r)*VV + n+0] : 0.f;
        bv.y = (n+1<VV)? a.Wsym[(k0+r)*VV + n+1] : 0.f;
        bv.z = (n+2<VV)? a.Wsym[(k0+r)*VV + n+2] : 0.f;
        bv.w = (n+3<VV)? a.Wsym[(k0+r)*VV + n+3] : 0.f;
      }
      *(float4*)&Bs[r*64 + c4] = bv;
    }
    __syncthreads();
    #pragma unroll
    for(int k=0;k<16;k++){
      float x0 = As[k*33 + ty*2], x1 = As[k*33 + ty*2 + 1];
      float4 b4 = *(const float4*)&Bs[k*64 + tx*4];
      a00 = fmaf(x0,b4.x,a00); a01 = fmaf(x0,b4.y,a01);
      a02 = fmaf(x0,b4.z,a02); a03 = fmaf(x0,b4.w,a03);
      a10 = fmaf(x1,b4.x,a10); a11 = fmaf(x1,b4.y,a11);
      a12 = fmaf(x1,b4.z,a12); a13 = fmaf(x1,b4.w,a13);
    }
    __syncthreads();
  }
  float accs[2][4] = {{a00,a01,a02,a03},{a10,a11,a12,a13}};
  #pragma unroll
  for(int i=0;i<2;i++){
    int ri = ty*2 + i;
    int m = m0 + ri;
    #pragma unroll
    for(int j=0;j<4;j++){
      int n = n0 + tx*4 + j;
      if(n < VV){
        bool allowed = false;
        #pragma unroll
        for(int o=0;o<OPTN;o++) allowed |= (sel[ri*OPTN + o] == n);
        a.cl[((size_t)t*BB + m)*VV + n] = accs[i][j] + a.bsym[n] + (allowed? 0.f : LOG_TINY);
      }
    }
  }
}

// ---- phase D: lse[9]; opts_logp; best; topo; sym_i; Abf build
__device__ void phaseD(const CoopArgs& a, float* sm){
  float* rm    = sm;            // [256]
  float* rs    = sm + 256;      // [256]
  float* lse_sh= sm + 512;      // [10]
  float* sacc  = sm + 528;      // [16]
  int*   ssym  = (int*)(sm + 544); // [10]
  int*   sbestp= (int*)(sm + 560);
  int b = blockIdx.x, tid = threadIdx.x;
  {
    const float* row = a.cl + ((size_t)9*BB + b)*VV;
    float mx = -1e30f, s_ = 0.f;
    for(int v=tid; v<VV; v+=NBLK){
      float val = row[v];
      if(val > mx){ s_ = s_*expf(mx - val) + 1.0f; mx = val; }
      else s_ += expf(val - mx);
    }
    rm[tid]=mx; rs[tid]=s_;
    __syncthreads();
    for(int s=128; s; s>>=1){
      if(tid < s){
        float m1=rm[tid], s1=rs[tid], m2=rm[tid+s], s2=rs[tid+s];
        float M = fmaxf(m1,m2);
        rs[tid] = s1*expf(m1-M) + s2*expf(m2-M);
        rm[tid] = M;
      }
      __syncthreads();
    }
    if(tid==0) lse_sh[9] = rm[0] + logf(rs[0]);
  }
  if(tid < 9) lse_sh[tid] = a.lse[tid*BB + b];
  __syncthreads();
  if(tid < OPTN){
    int o = tid;
    float acc = 0.f;
    for(int t=0;t<SEQN;t++){
      int base = ((b*OPTN + o)*4)*SEQN + t;
      int mk = a.gg[base + 3*SEQN];
      if(mk){
        int v = a.gg[base];
        float p = expf(a.cl[((size_t)t*BB + b)*VV + v] - lse_sh[t]);
        acc += logf(p + 1e-13f);
      }
    }
    sacc[o] = acc;
    a.out[OFF_OPTS + b*OPTN + o] = acc;
  }
  __syncthreads();
  if(tid==0){
    float mx = sacc[0]; int mi = 0;
    for(int o=1;o<OPTN;o++) if(sacc[o] > mx){ mx = sacc[o]; mi = o; }
    *sbestp = mi;
  }
  __syncthreads();
  int sbest = *sbestp;
  if(tid < 4*SEQN){
    int c = tid/SEQN, t = tid%SEQN;
    int val = a.gg[((b*OPTN + sbest)*4 + c)*SEQN + t];
    a.out[OFF_TOPO + c*(BB*SEQN) + b*SEQN + t] = (float)val;
    if(c==0){ a.sym_i[b*SEQN + t] = val; ssym[t] = val; }
  }
  __syncthreads();
  for(int idx = tid; idx < SEQN*D2; idx += NBLK){
    int t = idx >> 9, k = idx & 511;
    float val = (k < DD) ? a.emb[ssym[t]*DD + k] : a.ts[b*DD + (k-DD)];
    a.Abf[(size_t)(b*SEQN + t)*D2 + k] = f2bf(val);
  }
}

__global__ __launch_bounds__(256, 1) void k_coop(CoopArgs a){
  __shared__ __align__(16) float sm[3072];
  phase0(a, sm);
  gbar(a.bcnt, a.bgen);
  for(int t=0; t<SEQN; t++){
    phaseA(t, a, sm);
    gbar(a.bcnt, a.bgen);
    phaseC(t, a, sm);
    gbar(a.bcnt, a.bgen);
  }
  phaseD(a, sm);
}

// ---- fused prep: passthrough + WtokT + tokpack + WcT + barrier zero
__global__ void k_prep(const int* __restrict__ lhs, const int* __restrict__ lhs_mask,
                       const int* __restrict__ gg, const float* __restrict__ Wtok,
                       const float* __restrict__ tok_table, const float* __restrict__ Wc,
                       float* __restrict__ out, unsigned short* __restrict__ WtokB,
                       unsigned int* __restrict__ maskp, float* __restrict__ WcT,
                       int* __restrict__ bar){
  __shared__ float tile[32][65];
  int blk = blockIdx.x, tid = threadIdx.x;
  if(blk == 0 && tid < 64) bar[tid] = 0;
  if(blk < 642){
    int i = blk*256 + tid;
    if(i < BB) out[i] = (float)lhs[i];
    else if(i < 2*BB) out[i] = (float)lhs_mask[i - BB];
    else if(i < OFF_OPTS) out[i] = (float)gg[i - 2*BB];
  } else if(blk < 3154){
    int id = blk - 642;
    int n0 = (id % 157)*64, k0 = (id/157)*32;
    #pragma unroll
    for(int p=0;p<8;p++){
      int idx = tid + p*256;
      int kk = idx >> 6, nn = idx & 63;
      int n = n0 + nn;
      tile[kk][nn] = (n < VT) ? Wtok[(size_t)(k0+kk)*VT + n] : 0.f;
    }
    __syncthreads();
    #pragma unroll
    for(int p=0;p<4;p++){
      int idx = tid + p*256;
      int nn = idx >> 4, kk = (idx & 15)*2;
      int n = n0 + nn;
      if(n < VT){
        ushort2 v;
        v.x = f2bf(tile[kk][nn]);
        v.y = f2bf(tile[kk+1][nn]);
        *(ushort2*)&WtokB[(size_t)n*D2 + k0 + kk] = v;
      }
    }
  } else if(blk < 5154){
    int v = blk - 3154;
    int lane = tid & 63, wv = tid >> 6;
    for(int n0 = wv*64; n0 < VT; n0 += 256){
      int n = n0 + lane;
      float val = (n < VT) ? tok_table[(size_t)v*VT + n] : 0.f;
      unsigned long long m = __ballot(val != 0.f);
      if(lane == 0)  maskp[v*WPR + (n0>>5)]     = (unsigned int)m;
      if(lane == 32) maskp[v*WPR + (n0>>5) + 1] = (unsigned int)(m >> 32);
    }
  } else {
    int id = blk - 5154;  // [0,128)
    int k0 = (id >> 3)*32, n0 = (id & 7)*32;
    #pragma unroll
    for(int p=0;p<4;p++){
      int idx = tid + p*256;
      int kk = idx >> 5, nn = idx & 31;
      tile[kk][nn] = Wc[(k0+kk)*DD + n0 + nn];
    }
    __syncthreads();
    #pragma unroll
    for(int p=0;p<4;p++){
      int idx = tid + p*256;
      int nn = idx >> 5, kk2 = idx & 31;
      WcT[(size_t)(n0+nn)*D2 + k0 + kk2] = tile[kk2][nn];
    }
  }
}

// ---- exact_logit: bf16 MFMA GEMM 2560x10000 K=512 + bitmask epilogue
__global__ __launch_bounds__(256) void k_tok_mfma(
    const unsigned short* __restrict__ A, const unsigned short* __restrict__ Bw,
    const float* __restrict__ btok, const unsigned int* __restrict__ maskp,
    const int* __restrict__ sym_i, float* __restrict__ out){
  __shared__ unsigned short As[128*40];
  __shared__ unsigned short Bs[128*40];
  __shared__ float Cs[32][132];
  __shared__ float Bt[128];
  int tid = threadIdx.x;
  int lane = tid & 63, wave = tid >> 6;
  int c = lane & 15, q = lane >> 4;
  int wm = (wave >> 1)*64, wn = (wave & 1)*64;
  int m0 = blockIdx.y*128, n0 = blockIdx.x*128;
  if(tid < 128) Bt[tid] = (n0+tid < VT) ? btok[n0+tid] : 0.f;
  f32x4 acc[4][4];
  #pragma unroll
  for(int i=0;i<4;i++)
    #pragma unroll
    for(int j=0;j<4;j++) acc[i][j] = (f32x4){0.f,0.f,0.f,0.f};

  for(int k0=0;k0<D2;k0+=32){
    #pragma unroll
    for(int ci = tid; ci < 512; ci += 256){
      int row = ci >> 2, ko = (ci & 3)*8;
      float4 av = *(const float4*)(A + (size_t)(m0+row)*D2 + k0 + ko);
      *(float4*)(As + row*40 + ko) = av;
      int n = n0 + row;
      float4 bv = {0,0,0,0};
      if(n < VT) bv = *(const float4*)(Bw + (size_t)n*D2 + k0 + ko);
      *(float4*)(Bs + row*40 + ko) = bv;
    }
    __syncthreads();
    bf16x8 af[4], bf[4];
    #pragma unroll
    for(int i=0;i<4;i++) af[i] = *(const bf16x8*)(As + (wm + i*16 + c)*40 + q*8);
    #pragma unroll
    for(int j=0;j<4;j++) bf[j] = *(const bf16x8*)(Bs + (wn + j*16 + c)*40 + q*8);
    #pragma unroll
    for(int i=0;i<4;i++)
      #pragma unroll
      for(int j=0;j<4;j++)
        acc[i][j] = __builtin_amdgcn_mfma_f32_16x16x32_bf16(af[i], bf[j], acc[i][j], 0, 0, 0);
    __syncthreads();
  }
  for(int ch=0; ch<4; ch++){
    int rbase = (wm ? 16 : 0);
    #pragma unroll
    for(int j=0;j<4;j++)
      #pragma unroll
      for(int r=0;r<4;r++)
        Cs[rbase + q*4 + r][wn + j*16 + c] = acc[ch][j][r];
    __syncthreads();
    int col4 = (tid & 31)*4;
    int rowbase = (tid >> 5)*4;
    int n = n0 + col4;
    if(n < VT){
      #pragma unroll
      for(int g=0; g<4; g++){
        int rr = rowbase + g;
        int tr = (rr < 16) ? ch*16 + rr : 64 + ch*16 + (rr - 16);
        int m = m0 + tr;
        int s = sym_i[m];
        unsigned int w = maskp[s*WPR + (n0>>5) + (col4>>5)];
        float4 vv;
        vv.x = Cs[rr][col4+0] + Bt[col4+0] + (((w>>((col4+0)&31))&1) ? 0.f : LOG_TINY);
        vv.y = Cs[rr][col4+1] + Bt[col4+1] + (((w>>((col4+1)&31))&1) ? 0.f : LOG_TINY);
        vv.z = Cs[rr][col4+2] + Bt[col4+2] + (((w>>((col4+2)&31))&1) ? 0.f : LOG_TINY);
        vv.w = Cs[rr][col4+3] + Bt[col4+3] + (((w>>((col4+3)&31))&1) ? 0.f : LOG_TINY);
        *(float4*)&out[OFF_EXACT + (size_t)m*VT + n] = vv;
      }
    }
    __syncthreads();
  }
}

extern "C" void kernel_launch(void* const* d_in, const int* in_sizes, int n_in,
                              void* d_out, int out_size, void* d_ws, size_t ws_size,
                              hipStream_t stream) {
  const int*   lhs       = (const int*)  d_in[0];
  const int*   lhs_mask  = (const int*)  d_in[1];
  const float* tree_state= (const float*)d_in[2];
  const int*   gg        = (const int*)  d_in[3];
  const float* emb       = (const float*)d_in[4];
  const float* mem       = (const float*)d_in[5];
  const float* Wx        = (const float*)d_in[6];
  const float* Wh        = (const float*)d_in[7];
  const float* bx        = (const float*)d_in[8];
  const float* bh        = (const float*)d_in[9];
  const float* Wc        = (const float*)d_in[10];
  const float* bc        = (const float*)d_in[11];
  const float* Wsym      = (const float*)d_in[12];
  const float* bsym      = (const float*)d_in[13];
  const float* Wtok      = (const float*)d_in[14];
  const float* btok      = (const float*)d_in[15];
  const float* tok_table = (const float*)d_in[16];
  float* out = (float*)d_out;

  float* W    = (float*)d_ws;
  float* gh   = W;                          // 196608
  float* ts   = gh  + BB*D3;                // 65536
  float* soa  = ts  + BB*DD;                // 65536
  float* cl   = soa + BB*DD;                // 5,120,000
  float* EW   = cl  + (size_t)SEQN*BB*VV;   // 1,536,000
  float* lse  = EW  + (size_t)VV*D3;        // 2560
  float* WcT  = lse + SEQN*BB;              // 131072
  int*   sym_i= (int*)(WcT + DD*D2);        // 2560
  unsigned short* Abf  = (unsigned short*)(sym_i + BB*SEQN);      // 2560*512 u16
  unsigned short* WtokB= Abf + (size_t)BB*SEQN*D2;                // 10000*512 u16
  unsigned int* maskp  = (unsigned int*)(WtokB + (size_t)VT*D2);  // 2000*320 u32
  int* bar = (int*)(maskp + (size_t)VV*WPR);                      // 64 ints

  hipMemcpyAsync(ts, tree_state, BB*DD*sizeof(float), hipMemcpyDeviceToDevice, stream);

  k_prep<<<5282, 256, 0, stream>>>(lhs, lhs_mask, gg, Wtok, tok_table, Wc,
                                   out, WtokB, maskp, WcT, bar);

  CoopArgs ca;
  ca.lhs = lhs; ca.gg = gg; ca.tree_state = tree_state; ca.emb = emb; ca.mem = mem;
  ca.Wx = Wx; ca.Wh = Wh; ca.bx = bx; ca.bh = bh; ca.bc = bc;
  ca.Wsym = Wsym; ca.bsym = bsym;
  ca.EW = EW; ca.gh = gh; ca.soa = soa; ca.ts = ts; ca.cl = cl; ca.lse = lse; ca.WcT = WcT;
  ca.out = out; ca.sym_i = sym_i; ca.Abf = Abf;
  ca.bcnt = bar; ca.bgen = bar + 32;
  void* kargs[] = { &ca };
  hipLaunchCooperativeKernel((void*)k_coop, dim3(NBLK), dim3(256), kargs, 0, stream);

  k_tok_mfma<<<dim3((VT+127)/128, (BB*SEQN)/128), 256, 0, stream>>>(Abf, WtokB, btok, maskp, sym_i, out);
}